// Round 4
// baseline (2847.958 us; speedup 1.0000x reference)
//
#include <hip/hip_runtime.h>
#include <hip/hip_bf16.h>

typedef float f2 __attribute__((ext_vector_type(2)));
typedef float f4 __attribute__((ext_vector_type(4)));

#define BB 64
#define TT 2048
#define II 64
#define HH 128
#define OO 64

// ---------- bf16 helpers (explicit RNE, no API ambiguity) ----------
__device__ __forceinline__ unsigned short f32_to_bf16(float f) {
    unsigned u = __float_as_uint(f);
    unsigned r = (u + 0x7fffu + ((u >> 16) & 1u)) >> 16;
    return (unsigned short)r;
}
__device__ __forceinline__ unsigned pack_bf(float lo, float hi) {
    return ((unsigned)f32_to_bf16(hi) << 16) | (unsigned)f32_to_bf16(lo);
}
__device__ __forceinline__ float bf_lo(unsigned u) { return __uint_as_float(u << 16); }
__device__ __forceinline__ float bf_hi(unsigned u) { return __uint_as_float(u & 0xffff0000u); }

// =====================================================================
// Kernel 1: xp[d][b][t][h] (bf16 pairs) = x[b,t,:]·Wih_d[h,:] + bih + bhh
// Fully parallel. 1024 blocks = d(2) × b(64) × ttile(8 of 256), 256 thr.
// Wave w handles t_loc in [w*64,(w+1)*64); lane l computes h pair (2l,2l+1).
// x row is uniform across the wave -> broadcast LDS reads, conflict-free.
// =====================================================================
__global__ __launch_bounds__(256, 1)
void xp_kernel(const float* __restrict__ x,
               const float* __restrict__ Wih_f, const float* __restrict__ bih_f,
               const float* __restrict__ bhh_f,
               const float* __restrict__ Wih_b, const float* __restrict__ bih_b,
               const float* __restrict__ bhh_b,
               unsigned* __restrict__ xp)
{
    const int blk = blockIdx.x;
    const int tt = blk & 7;
    const int b  = (blk >> 3) & 63;
    const int d  = blk >> 9;
    const float* __restrict__ Wih = d ? Wih_b : Wih_f;
    const float* __restrict__ bih = d ? bih_b : bih_f;
    const float* __restrict__ bhh = d ? bhh_b : bhh_f;

    const int tid = threadIdx.x;
    const int w   = tid >> 6;
    const int l   = tid & 63;

    __shared__ float xs[256 * II];   // 64 KiB

    // stage x[b, tt*256 : +256, :] — contiguous 64 KiB, coalesced f4 loads
    const float* xsrc = x + ((size_t)b * TT + (size_t)tt * 256) * II;
    for (int i = tid; i < 256 * II / 4; i += 256)
        ((f4*)xs)[i] = ((const f4*)xsrc)[i];

    // weights: rows 2l, 2l+1 of Wih (64 f32 each) into registers
    f2 w0[32], w1[32];
    {
        const f4* s0 = (const f4*)(Wih + (size_t)(2 * l) * II);
        const f4* s1 = (const f4*)(Wih + (size_t)(2 * l + 1) * II);
        #pragma unroll
        for (int m = 0; m < 16; ++m) {
            f4 v0 = s0[m], v1 = s1[m];
            w0[2 * m] = (f2){v0.x, v0.y}; w0[2 * m + 1] = (f2){v0.z, v0.w};
            w1[2 * m] = (f2){v1.x, v1.y}; w1[2 * m + 1] = (f2){v1.z, v1.w};
        }
    }
    const float bias0 = bih[2 * l]     + bhh[2 * l];
    const float bias1 = bih[2 * l + 1] + bhh[2 * l + 1];
    __syncthreads();

    unsigned* xpd = xp + ((size_t)(d * BB + b) * TT + (size_t)tt * 256) * (HH / 2);
    for (int ti = 0; ti < 64; ++ti) {
        const int t_loc = w * 64 + ti;
        const f4* xr = (const f4*)(xs + t_loc * II);
        f2 a0 = (f2){0, 0}, a0b = (f2){0, 0}, a1 = (f2){0, 0}, a1b = (f2){0, 0};
        #pragma unroll
        for (int m = 0; m < 16; ++m) {
            f4 v = xr[m];
            f2 lo = (f2){v.x, v.y}, hi = (f2){v.z, v.w};
            a0  += w0[2 * m] * lo;  a0b += w0[2 * m + 1] * hi;
            a1  += w1[2 * m] * lo;  a1b += w1[2 * m + 1] * hi;
        }
        float z0 = a0.x + a0.y + a0b.x + a0b.y + bias0;
        float z1 = a1.x + a1.y + a1b.x + a1b.y + bias1;
        xpd[(size_t)t_loc * (HH / 2) + l] = pack_bf(z0, z1);
    }
}

// =====================================================================
// Kernel 2: the serial recurrence. ONE WAVE per (b,d) — no barriers, no
// waited vmem on the critical path. Whh rows (f32) in registers; h (f32)
// broadcast through a tiny LDS double buffer with uniform ds_read_b128
// (conflict-free); xp streamed in with +2-step prefetch; y streamed out
// as bf16 (stores are never waited — there is no barrier to drain them).
// =====================================================================
__global__ __launch_bounds__(64, 1)
void rnn_serial(const float* __restrict__ Whh_f, const float* __restrict__ Whh_b,
                const unsigned* __restrict__ xp, unsigned* __restrict__ y)
{
    const int l = threadIdx.x;
    const int b = blockIdx.x & 63;
    const int d = blockIdx.x >> 6;
    const float* __restrict__ Whh = d ? Whh_b : Whh_f;

    __shared__ float hb[2][HH];

    // rows 2l, 2l+1 of Whh (128 f32 each) -> 256 VGPRs
    f2 wr0[64], wr1[64];
    {
        const f4* s0 = (const f4*)(Whh + (size_t)(2 * l) * HH);
        const f4* s1 = (const f4*)(Whh + (size_t)(2 * l + 1) * HH);
        #pragma unroll
        for (int m = 0; m < 32; ++m) {
            f4 v0 = s0[m], v1 = s1[m];
            wr0[2 * m] = (f2){v0.x, v0.y}; wr0[2 * m + 1] = (f2){v0.z, v0.w};
            wr1[2 * m] = (f2){v1.x, v1.y}; wr1[2 * m + 1] = (f2){v1.z, v1.w};
        }
    }

    ((f2*)hb[0])[l] = (f2){0.f, 0.f};   // h0 = 0

    const size_t base = (size_t)(d * BB + b) * TT * (HH / 2);
    const unsigned* xpl = xp + base + l;
    unsigned*       yl  = y  + base + l;

    // t mapping: step s -> t = d ? TT-1-s : s
    const int t0 = d ? (TT - 1) : 0;
    const int dt = d ? -1 : 1;

    unsigned xcur = xpl[(size_t)t0 * (HH / 2)];
    unsigned xnxt = xpl[(size_t)(t0 + dt) * (HH / 2)];

    #pragma unroll 2
    for (int s = 0; s < TT; ++s) {
        const int cur = s & 1, nxt = cur ^ 1;

        // prefetch xp for s+2 (L3-resident; never blocks — used 2 iters later)
        unsigned xfar = 0;
        if (s + 2 < TT) xfar = xpl[(size_t)(t0 + dt * (s + 2)) * (HH / 2)];

        // z = Whh·h + xp  (uniform broadcast reads of h; 4 accum chains)
        const f4* hr = (const f4*)hb[cur];
        f2 a0 = (f2){0, 0}, a0b = (f2){0, 0}, a1 = (f2){0, 0}, a1b = (f2){0, 0};
        #pragma unroll
        for (int m = 0; m < 32; ++m) {
            f4 v = hr[m];
            f2 lo = (f2){v.x, v.y}, hi = (f2){v.z, v.w};
            a0  += wr0[2 * m] * lo;  a0b += wr0[2 * m + 1] * hi;
            a1  += wr1[2 * m] * lo;  a1b += wr1[2 * m + 1] * hi;
        }
        float z0 = a0.x + a0.y + a0b.x + a0b.y + bf_lo(xcur);
        float z1 = a1.x + a1.y + a1b.x + a1b.y + bf_hi(xcur);

        // tanh(z) = 1 - 2/(e^{2z}+1), inf-safe
        float e0 = __expf(2.f * z0);
        float e1 = __expf(2.f * z1);
        float h0 = 1.f - __fdividef(2.f, e0 + 1.f);
        float h1 = 1.f - __fdividef(2.f, e1 + 1.f);

        ((f2*)hb[nxt])[l] = (f2){h0, h1};          // for next step (lgkm only)
        yl[(size_t)(t0 + dt * s) * (HH / 2)] = pack_bf(h0, h1);  // streamed, never waited

        xcur = xnxt; xnxt = xfar;
    }
}

// =====================================================================
// Kernel 3: out[b][t][o] = Wout[o,:]·[y_f;y_b] + bout. Fully parallel.
// 2048 blocks = b(64) × ttile(32 of 64), 256 thr. y tile staged to LDS
// as f32; lane pair (o, K-half) with intra-wave shfl reduce.
// =====================================================================
__global__ __launch_bounds__(256, 1)
void out_kernel(const unsigned* __restrict__ y, const float* __restrict__ Wout,
                const float* __restrict__ bout, float* __restrict__ out)
{
    const int blk = blockIdx.x;
    const int tt = blk & 31;
    const int b  = blk >> 5;
    const int tid = threadIdx.x;
    const int w = tid >> 6, l = tid & 63;

    __shared__ float ys[64][2 * HH];   // 64 KiB, y as f32: [:128]=fwd, [128:]=bwd

    const unsigned* yf = y + ((size_t)(0 * BB + b) * TT + (size_t)tt * 64) * (HH / 2);
    const unsigned* yb = y + ((size_t)(1 * BB + b) * TT + (size_t)tt * 64) * (HH / 2);
    for (int i = tid; i < 64 * (HH / 2); i += 256) {
        const int t_loc = i >> 6, hp = i & 63;
        unsigned vf = yf[i], vb = yb[i];
        ys[t_loc][2 * hp]          = bf_lo(vf);
        ys[t_loc][2 * hp + 1]      = bf_hi(vf);
        ys[t_loc][HH + 2 * hp]     = bf_lo(vb);
        ys[t_loc][HH + 2 * hp + 1] = bf_hi(vb);
    }

    // role: o = 32*(w&1) + (l>>1); ks = l&1 selects K-half (128 of 256)
    const int o  = 32 * (w & 1) + (l >> 1);
    const int ks = l & 1;
    f2 wv[64];
    {
        const f4* s = (const f4*)(Wout + (size_t)o * (2 * HH) + (size_t)ks * HH);
        #pragma unroll
        for (int m = 0; m < 32; ++m) {
            f4 v = s[m];
            wv[2 * m] = (f2){v.x, v.y}; wv[2 * m + 1] = (f2){v.z, v.w};
        }
    }
    const float bo = bout[o];
    __syncthreads();

    for (int i = 0; i < 32; ++i) {
        const int t_loc = 2 * i + (w >> 1);
        const f4* yr = (const f4*)(&ys[t_loc][ks * HH]);
        f2 acc = (f2){0, 0}, accb = (f2){0, 0};
        #pragma unroll
        for (int m = 0; m < 32; ++m) {
            f4 v = yr[m];
            acc  += wv[2 * m]     * (f2){v.x, v.y};
            accb += wv[2 * m + 1] * (f2){v.z, v.w};
        }
        float r = acc.x + acc.y + accb.x + accb.y;
        r += __shfl_xor(r, 1);
        if (ks == 0)
            out[((size_t)b * TT + (size_t)tt * 64 + t_loc) * OO + o] = r + bo;
    }
}

// =====================================================================
// Fallback (ws too small): known-good fused kernel from round 3 (1689 us).
// =====================================================================
__global__ __launch_bounds__(256, 1)
void birnn_fused(const float* __restrict__ x,
                 const float* __restrict__ Wih_f, const float* __restrict__ Whh_f,
                 const float* __restrict__ bih_f, const float* __restrict__ bhh_f,
                 const float* __restrict__ Wih_b, const float* __restrict__ Whh_b,
                 const float* __restrict__ bih_b, const float* __restrict__ bhh_b,
                 const float* __restrict__ Wout, const float* __restrict__ bout,
                 float* __restrict__ out)
{
    const int tid = threadIdx.x;
    const int b   = blockIdx.x & (BB - 1);
    const int d   = blockIdx.x >> 6;
    const float* __restrict__ Wih = d ? Wih_b : Wih_f;
    const float* __restrict__ Whh = d ? Whh_b : Whh_f;
    const float* __restrict__ bih = d ? bih_b : bih_f;
    const float* __restrict__ bhh = d ? bhh_b : bhh_f;
    const int j = tid >> 1, p = tid & 1, o = tid >> 2, os = tid & 3;
    __shared__ float hbuf[2][HH];
    __shared__ float xbuf[2][II];
    f2 whh[32], wih[16], wo[16];
    {
        const f4* s4 = (const f4*)(Whh + (size_t)j * HH + p * 64);
        #pragma unroll
        for (int m = 0; m < 16; ++m) { f4 v = s4[m]; whh[2*m]=(f2){v.x,v.y}; whh[2*m+1]=(f2){v.z,v.w}; }
    }
    {
        const f4* s4 = (const f4*)(Wih + (size_t)j * II + p * 32);
        #pragma unroll
        for (int m = 0; m < 8; ++m) { f4 v = s4[m]; wih[2*m]=(f2){v.x,v.y}; wih[2*m+1]=(f2){v.z,v.w}; }
    }
    {
        const f4* s4 = (const f4*)(Wout + (size_t)o * (2*HH) + d*HH + os*32);
        #pragma unroll
        for (int m = 0; m < 8; ++m) { f4 v = s4[m]; wo[2*m]=(f2){v.x,v.y}; wo[2*m+1]=(f2){v.z,v.w}; }
    }
    const float bj = bih[j] + bhh[j];
    const float bo = d ? 0.f : bout[o];
    const float* __restrict__ xb   = x   + (size_t)b * TT * II;
    float*       __restrict__ outb = out + (size_t)b * TT * OO;
    const int t0 = d ? (TT - 1) : 0;
    const int dt = d ? -1 : 1;
    float xpre = 0.f;
    if (tid < II) {
        xbuf[0][tid] = xb[(size_t)t0 * II + tid];
        xpre = xb[(size_t)(t0 + dt) * II + tid];
    }
    if (tid < HH) hbuf[0][tid] = 0.f;
    __syncthreads();
    #pragma unroll 2
    for (int s = 0; s < TT; ++s) {
        const int cur = s & 1, nxt = cur ^ 1;
        if (s > 0) {
            const f4* hv4 = (const f4*)(&hbuf[cur][os * 32]);
            f2 acc = (f2){0.f, 0.f};
            #pragma unroll
            for (int m = 0; m < 8; ++m) { f4 h4 = hv4[m]; acc += wo[2*m]*(f2){h4.x,h4.y}; acc += wo[2*m+1]*(f2){h4.z,h4.w}; }
            float v = acc.x + acc.y;
            v += __shfl_xor(v, 1); v += __shfl_xor(v, 2);
            if (os == 0) atomicAdd(&outb[(size_t)(t0 + dt*(s-1)) * OO + o], v + bo);
        }
        {
            const f4* hv4 = (const f4*)(&hbuf[cur][p * 64]);
            const f4* xv4 = (const f4*)(&xbuf[cur][p * 32]);
            f2 acc = (f2){0.f, 0.f};
            #pragma unroll
            for (int m = 0; m < 16; ++m) { f4 h4 = hv4[m]; acc += whh[2*m]*(f2){h4.x,h4.y}; acc += whh[2*m+1]*(f2){h4.z,h4.w}; }
            #pragma unroll
            for (int m = 0; m < 8; ++m) { f4 x4 = xv4[m]; acc += wih[2*m]*(f2){x4.x,x4.y}; acc += wih[2*m+1]*(f2){x4.z,x4.w}; }
            float z = acc.x + acc.y;
            z += __shfl_xor(z, 1);
            z += bj;
            float e = __expf(2.f * z);
            float h = 1.f - __fdividef(2.f, e + 1.f);
            if (p == 0) hbuf[nxt][j] = h;
        }
        if (tid < II) {
            xbuf[nxt][tid] = xpre;
            if (s + 2 < TT) xpre = xb[(size_t)(t0 + dt*(s+2)) * II + tid];
        }
        __syncthreads();
    }
    {
        const f4* hv4 = (const f4*)(&hbuf[TT & 1][os * 32]);
        f2 acc = (f2){0.f, 0.f};
        #pragma unroll
        for (int m = 0; m < 8; ++m) { f4 h4 = hv4[m]; acc += wo[2*m]*(f2){h4.x,h4.y}; acc += wo[2*m+1]*(f2){h4.z,h4.w}; }
        float v = acc.x + acc.y;
        v += __shfl_xor(v, 1); v += __shfl_xor(v, 2);
        if (os == 0) atomicAdd(&outb[(size_t)(t0 + dt*(TT-1)) * OO + o], v + bo);
    }
}

extern "C" void kernel_launch(void* const* d_in, const int* in_sizes, int n_in,
                              void* d_out, int out_size, void* d_ws, size_t ws_size,
                              hipStream_t stream) {
    const float* x     = (const float*)d_in[0];
    const float* Wih_f = (const float*)d_in[1];
    const float* Whh_f = (const float*)d_in[2];
    const float* bih_f = (const float*)d_in[3];
    const float* bhh_f = (const float*)d_in[4];
    const float* Wih_b = (const float*)d_in[5];
    const float* Whh_b = (const float*)d_in[6];
    const float* bih_b = (const float*)d_in[7];
    const float* bhh_b = (const float*)d_in[8];
    const float* Wout  = (const float*)d_in[9];
    const float* bout  = (const float*)d_in[10];
    float* out = (float*)d_out;

    const size_t xp_bytes = (size_t)2 * BB * TT * (HH / 2) * 4;  // 64 MiB (bf16 pairs)
    const size_t y_bytes  = xp_bytes;                             // 64 MiB
    if (ws_size >= xp_bytes + y_bytes) {
        unsigned* xp_ws = (unsigned*)d_ws;
        unsigned* y_ws  = (unsigned*)((char*)d_ws + xp_bytes);
        xp_kernel<<<dim3(1024), dim3(256), 0, stream>>>(
            x, Wih_f, bih_f, bhh_f, Wih_b, bih_b, bhh_b, xp_ws);
        rnn_serial<<<dim3(2 * BB), dim3(64), 0, stream>>>(Whh_f, Whh_b, xp_ws, y_ws);
        out_kernel<<<dim3(2048), dim3(256), 0, stream>>>(y_ws, Wout, bout, out);
    } else {
        hipMemsetAsync(d_out, 0, (size_t)out_size * sizeof(float), stream);
        birnn_fused<<<dim3(2 * BB), dim3(256), 0, stream>>>(
            x, Wih_f, Whh_f, bih_f, bhh_f,
            Wih_b, Whh_b, bih_b, bhh_b, Wout, bout, out);
    }
}

// Round 5
// 1336.157 us; speedup vs baseline: 2.1315x; 2.1315x over previous
//
#include <hip/hip_runtime.h>
#include <hip/hip_bf16.h>

typedef float f2 __attribute__((ext_vector_type(2)));
typedef float f4 __attribute__((ext_vector_type(4)));

#define BB 64
#define TT 2048
#define II 64
#define HH 128
#define OO 64

// ---------- bf16 helpers (explicit RNE) ----------
__device__ __forceinline__ unsigned short f32_to_bf16(float f) {
    unsigned u = __float_as_uint(f);
    unsigned r = (u + 0x7fffu + ((u >> 16) & 1u)) >> 16;
    return (unsigned short)r;
}
__device__ __forceinline__ unsigned pack_bf(float lo, float hi) {
    return ((unsigned)f32_to_bf16(hi) << 16) | (unsigned)f32_to_bf16(lo);
}
__device__ __forceinline__ float bf_lo(unsigned u) { return __uint_as_float(u << 16); }
__device__ __forceinline__ float bf_hi(unsigned u) { return __uint_as_float(u & 0xffff0000u); }

// =====================================================================
// Kernel 1 (unchanged, known-good): xp[d][b][t][pair] (bf16 pairs)
//   = x[b,t,:]·Wih_d[h,:] + bih + bhh
// =====================================================================
__global__ __launch_bounds__(256, 1)
void xp_kernel(const float* __restrict__ x,
               const float* __restrict__ Wih_f, const float* __restrict__ bih_f,
               const float* __restrict__ bhh_f,
               const float* __restrict__ Wih_b, const float* __restrict__ bih_b,
               const float* __restrict__ bhh_b,
               unsigned* __restrict__ xp)
{
    const int blk = blockIdx.x;
    const int tt = blk & 7;
    const int b  = (blk >> 3) & 63;
    const int d  = blk >> 9;
    const float* __restrict__ Wih = d ? Wih_b : Wih_f;
    const float* __restrict__ bih = d ? bih_b : bih_f;
    const float* __restrict__ bhh = d ? bhh_b : bhh_f;

    const int tid = threadIdx.x;
    const int w   = tid >> 6;
    const int l   = tid & 63;

    __shared__ float xs[256 * II];   // 64 KiB

    const float* xsrc = x + ((size_t)b * TT + (size_t)tt * 256) * II;
    for (int i = tid; i < 256 * II / 4; i += 256)
        ((f4*)xs)[i] = ((const f4*)xsrc)[i];

    f2 w0[32], w1[32];
    {
        const f4* s0 = (const f4*)(Wih + (size_t)(2 * l) * II);
        const f4* s1 = (const f4*)(Wih + (size_t)(2 * l + 1) * II);
        #pragma unroll
        for (int m = 0; m < 16; ++m) {
            f4 v0 = s0[m], v1 = s1[m];
            w0[2 * m] = (f2){v0.x, v0.y}; w0[2 * m + 1] = (f2){v0.z, v0.w};
            w1[2 * m] = (f2){v1.x, v1.y}; w1[2 * m + 1] = (f2){v1.z, v1.w};
        }
    }
    const float bias0 = bih[2 * l]     + bhh[2 * l];
    const float bias1 = bih[2 * l + 1] + bhh[2 * l + 1];
    __syncthreads();

    unsigned* xpd = xp + ((size_t)(d * BB + b) * TT + (size_t)tt * 256) * (HH / 2);
    for (int ti = 0; ti < 64; ++ti) {
        const int t_loc = w * 64 + ti;
        const f4* xr = (const f4*)(xs + t_loc * II);
        f2 a0 = (f2){0, 0}, a0b = (f2){0, 0}, a1 = (f2){0, 0}, a1b = (f2){0, 0};
        #pragma unroll
        for (int m = 0; m < 16; ++m) {
            f4 v = xr[m];
            f2 lo = (f2){v.x, v.y}, hi = (f2){v.z, v.w};
            a0  += w0[2 * m] * lo;  a0b += w0[2 * m + 1] * hi;
            a1  += w1[2 * m] * lo;  a1b += w1[2 * m + 1] * hi;
        }
        float z0 = a0.x + a0.y + a0b.x + a0b.y + bias0;
        float z1 = a1.x + a1.y + a1b.x + a1b.y + bias1;
        xpd[(size_t)t_loc * (HH / 2) + l] = pack_bf(z0, z1);
    }
}

// =====================================================================
// Kernel 2: serial recurrence, v2.
//   2 waves per (b,d); ONE row per lane -> 128 f32 weights/lane (fits in
//   VGPRs; waves_per_eu(1,1) pins the RA budget at 512 so it can't remat
//   the weight loads back into the loop — round-4 failure mode).
//   Cross-wave h exchange: LDS double buffer + raw {lgkmcnt(0); s_barrier}
//   in one memory-clobbered asm — NO vmcnt drain, so the y store and xp
//   prefetch never sit on the critical path.
// =====================================================================
__global__
__attribute__((amdgpu_flat_work_group_size(128, 128), amdgpu_waves_per_eu(1, 1)))
void rnn_serial2(const float* __restrict__ Whh_f, const float* __restrict__ Whh_b,
                 const unsigned* __restrict__ xp, unsigned short* __restrict__ y)
{
    const int j = threadIdx.x;          // row 0..127
    const int b = blockIdx.x & 63;
    const int d = blockIdx.x >> 6;
    const float* __restrict__ Whh = d ? Whh_b : Whh_f;

    __shared__ float hb[2][HH];

    // row j of Whh (128 f32) -> 64 f2 in registers
    f2 wr[64];
    {
        const f4* s0 = (const f4*)(Whh + (size_t)j * HH);
        #pragma unroll
        for (int m = 0; m < 32; ++m) {
            f4 v = s0[m];
            wr[2 * m]     = (f2){v.x, v.y};
            wr[2 * m + 1] = (f2){v.z, v.w};
        }
    }

    hb[0][j] = 0.f;   // h0

    const size_t base_pair = (size_t)(d * BB + b) * TT * (HH / 2);
    const unsigned*  xpl = xp + base_pair + (j >> 1);
    unsigned short*  yl  = y  + base_pair * 2 + j;
    const bool hi_half = (j & 1);

    const int t0 = d ? (TT - 1) : 0;
    const int dt = d ? -1 : 1;

    unsigned xc = xpl[(size_t)t0 * (HH / 2)];
    unsigned xn = xpl[(size_t)(t0 + dt) * (HH / 2)];

    asm volatile("s_waitcnt lgkmcnt(0)\n\ts_barrier" ::: "memory");

    #pragma unroll 2
    for (int s = 0; s < TT; ++s) {
        const int cur = s & 1, nxt = cur ^ 1;

        // prefetch xp for s+2 — never waited on this iteration
        unsigned xf = 0;
        if (s + 2 < TT) xf = xpl[(size_t)(t0 + dt * (s + 2)) * (HH / 2)];

        // z_j = Whh[j,:]·h  — uniform (broadcast) LDS reads, 4 accum chains
        const f4* hr = (const f4*)hb[cur];
        f2 a0 = (f2){0, 0}, a1 = (f2){0, 0}, a2 = (f2){0, 0}, a3 = (f2){0, 0};
        #pragma unroll
        for (int m = 0; m < 16; ++m) {
            f4 v0 = hr[2 * m], v1 = hr[2 * m + 1];
            a0 += wr[4 * m]     * (f2){v0.x, v0.y};
            a1 += wr[4 * m + 1] * (f2){v0.z, v0.w};
            a2 += wr[4 * m + 2] * (f2){v1.x, v1.y};
            a3 += wr[4 * m + 3] * (f2){v1.z, v1.w};
        }
        f2 at = (a0 + a1) + (a2 + a3);
        float z = at.x + at.y;
        z += hi_half ? bf_hi(xc) : bf_lo(xc);

        // tanh(z) = 1 - 2/(e^{2z}+1), inf-safe
        float e = __expf(2.f * z);
        float h = 1.f - __fdividef(2.f, e + 1.f);

        yl[(size_t)(t0 + dt * s) * HH] = f32_to_bf16(h);  // streamed, never waited
        hb[nxt][j] = h;

        // make h visible to the sibling wave: LDS-only wait + raw barrier
        asm volatile("s_waitcnt lgkmcnt(0)\n\ts_barrier" ::: "memory");

        xc = xn; xn = xf;
    }
}

// =====================================================================
// Kernel 3 (unchanged, known-good): out[b][t][o] = Wout·[y_f;y_b] + bout
// =====================================================================
__global__ __launch_bounds__(256, 1)
void out_kernel(const unsigned* __restrict__ y, const float* __restrict__ Wout,
                const float* __restrict__ bout, float* __restrict__ out)
{
    const int blk = blockIdx.x;
    const int tt = blk & 31;
    const int b  = blk >> 5;
    const int tid = threadIdx.x;
    const int w = tid >> 6, l = tid & 63;

    __shared__ float ys[64][2 * HH];   // 64 KiB

    const unsigned* yf = y + ((size_t)(0 * BB + b) * TT + (size_t)tt * 64) * (HH / 2);
    const unsigned* yb = y + ((size_t)(1 * BB + b) * TT + (size_t)tt * 64) * (HH / 2);
    for (int i = tid; i < 64 * (HH / 2); i += 256) {
        const int t_loc = i >> 6, hp = i & 63;
        unsigned vf = yf[i], vb = yb[i];
        ys[t_loc][2 * hp]          = bf_lo(vf);
        ys[t_loc][2 * hp + 1]      = bf_hi(vf);
        ys[t_loc][HH + 2 * hp]     = bf_lo(vb);
        ys[t_loc][HH + 2 * hp + 1] = bf_hi(vb);
    }

    const int o  = 32 * (w & 1) + (l >> 1);
    const int ks = l & 1;
    f2 wv[64];
    {
        const f4* s = (const f4*)(Wout + (size_t)o * (2 * HH) + (size_t)ks * HH);
        #pragma unroll
        for (int m = 0; m < 32; ++m) {
            f4 v = s[m];
            wv[2 * m] = (f2){v.x, v.y}; wv[2 * m + 1] = (f2){v.z, v.w};
        }
    }
    const float bo = bout[o];
    __syncthreads();

    for (int i = 0; i < 32; ++i) {
        const int t_loc = 2 * i + (w >> 1);
        const f4* yr = (const f4*)(&ys[t_loc][ks * HH]);
        f2 acc = (f2){0, 0}, accb = (f2){0, 0};
        #pragma unroll
        for (int m = 0; m < 32; ++m) {
            f4 v = yr[m];
            acc  += wv[2 * m]     * (f2){v.x, v.y};
            accb += wv[2 * m + 1] * (f2){v.z, v.w};
        }
        float r = acc.x + acc.y + accb.x + accb.y;
        r += __shfl_xor(r, 1);
        if (ks == 0)
            out[((size_t)b * TT + (size_t)tt * 64 + t_loc) * OO + o] = r + bo;
    }
}

// =====================================================================
// Fallback (ws too small): known-good fused kernel from round 3 (1689 us).
// =====================================================================
__global__ __launch_bounds__(256, 1)
void birnn_fused(const float* __restrict__ x,
                 const float* __restrict__ Wih_f, const float* __restrict__ Whh_f,
                 const float* __restrict__ bih_f, const float* __restrict__ bhh_f,
                 const float* __restrict__ Wih_b, const float* __restrict__ Whh_b,
                 const float* __restrict__ bih_b, const float* __restrict__ bhh_b,
                 const float* __restrict__ Wout, const float* __restrict__ bout,
                 float* __restrict__ out)
{
    const int tid = threadIdx.x;
    const int b   = blockIdx.x & (BB - 1);
    const int d   = blockIdx.x >> 6;
    const float* __restrict__ Wih = d ? Wih_b : Wih_f;
    const float* __restrict__ Whh = d ? Whh_b : Whh_f;
    const float* __restrict__ bih = d ? bih_b : bih_f;
    const float* __restrict__ bhh = d ? bhh_b : bhh_f;
    const int j = tid >> 1, p = tid & 1, o = tid >> 2, os = tid & 3;
    __shared__ float hbuf[2][HH];
    __shared__ float xbuf[2][II];
    f2 whh[32], wih[16], wo[16];
    {
        const f4* s4 = (const f4*)(Whh + (size_t)j * HH + p * 64);
        #pragma unroll
        for (int m = 0; m < 16; ++m) { f4 v = s4[m]; whh[2*m]=(f2){v.x,v.y}; whh[2*m+1]=(f2){v.z,v.w}; }
    }
    {
        const f4* s4 = (const f4*)(Wih + (size_t)j * II + p * 32);
        #pragma unroll
        for (int m = 0; m < 8; ++m) { f4 v = s4[m]; wih[2*m]=(f2){v.x,v.y}; wih[2*m+1]=(f2){v.z,v.w}; }
    }
    {
        const f4* s4 = (const f4*)(Wout + (size_t)o * (2*HH) + d*HH + os*32);
        #pragma unroll
        for (int m = 0; m < 8; ++m) { f4 v = s4[m]; wo[2*m]=(f2){v.x,v.y}; wo[2*m+1]=(f2){v.z,v.w}; }
    }
    const float bj = bih[j] + bhh[j];
    const float bo = d ? 0.f : bout[o];
    const float* __restrict__ xb   = x   + (size_t)b * TT * II;
    float*       __restrict__ outb = out + (size_t)b * TT * OO;
    const int t0 = d ? (TT - 1) : 0;
    const int dt = d ? -1 : 1;
    float xpre = 0.f;
    if (tid < II) {
        xbuf[0][tid] = xb[(size_t)t0 * II + tid];
        xpre = xb[(size_t)(t0 + dt) * II + tid];
    }
    if (tid < HH) hbuf[0][tid] = 0.f;
    __syncthreads();
    #pragma unroll 2
    for (int s = 0; s < TT; ++s) {
        const int cur = s & 1, nxt = cur ^ 1;
        if (s > 0) {
            const f4* hv4 = (const f4*)(&hbuf[cur][os * 32]);
            f2 acc = (f2){0.f, 0.f};
            #pragma unroll
            for (int m = 0; m < 8; ++m) { f4 h4 = hv4[m]; acc += wo[2*m]*(f2){h4.x,h4.y}; acc += wo[2*m+1]*(f2){h4.z,h4.w}; }
            float v = acc.x + acc.y;
            v += __shfl_xor(v, 1); v += __shfl_xor(v, 2);
            if (os == 0) atomicAdd(&outb[(size_t)(t0 + dt*(s-1)) * OO + o], v + bo);
        }
        {
            const f4* hv4 = (const f4*)(&hbuf[cur][p * 64]);
            const f4* xv4 = (const f4*)(&xbuf[cur][p * 32]);
            f2 acc = (f2){0.f, 0.f};
            #pragma unroll
            for (int m = 0; m < 16; ++m) { f4 h4 = hv4[m]; acc += whh[2*m]*(f2){h4.x,h4.y}; acc += whh[2*m+1]*(f2){h4.z,h4.w}; }
            #pragma unroll
            for (int m = 0; m < 8; ++m) { f4 x4 = xv4[m]; acc += wih[2*m]*(f2){x4.x,x4.y}; acc += wih[2*m+1]*(f2){x4.z,x4.w}; }
            float z = acc.x + acc.y;
            z += __shfl_xor(z, 1);
            z += bj;
            float e = __expf(2.f * z);
            float h = 1.f - __fdividef(2.f, e + 1.f);
            if (p == 0) hbuf[nxt][j] = h;
        }
        if (tid < II) {
            xbuf[nxt][tid] = xpre;
            if (s + 2 < TT) xpre = xb[(size_t)(t0 + dt*(s+2)) * II + tid];
        }
        __syncthreads();
    }
    {
        const f4* hv4 = (const f4*)(&hbuf[TT & 1][os * 32]);
        f2 acc = (f2){0.f, 0.f};
        #pragma unroll
        for (int m = 0; m < 8; ++m) { f4 h4 = hv4[m]; acc += wo[2*m]*(f2){h4.x,h4.y}; acc += wo[2*m+1]*(f2){h4.z,h4.w}; }
        float v = acc.x + acc.y;
        v += __shfl_xor(v, 1); v += __shfl_xor(v, 2);
        if (os == 0) atomicAdd(&outb[(size_t)(t0 + dt*(TT-1)) * OO + o], v + bo);
    }
}

extern "C" void kernel_launch(void* const* d_in, const int* in_sizes, int n_in,
                              void* d_out, int out_size, void* d_ws, size_t ws_size,
                              hipStream_t stream) {
    const float* x     = (const float*)d_in[0];
    const float* Wih_f = (const float*)d_in[1];
    const float* Whh_f = (const float*)d_in[2];
    const float* bih_f = (const float*)d_in[3];
    const float* bhh_f = (const float*)d_in[4];
    const float* Wih_b = (const float*)d_in[5];
    const float* Whh_b = (const float*)d_in[6];
    const float* bih_b = (const float*)d_in[7];
    const float* bhh_b = (const float*)d_in[8];
    const float* Wout  = (const float*)d_in[9];
    const float* bout  = (const float*)d_in[10];
    float* out = (float*)d_out;

    const size_t xp_bytes = (size_t)2 * BB * TT * (HH / 2) * 4;  // 64 MiB (bf16 pairs)
    const size_t y_bytes  = xp_bytes;                             // 64 MiB
    if (ws_size >= xp_bytes + y_bytes) {
        unsigned*       xp_ws = (unsigned*)d_ws;
        unsigned*       y_ws  = (unsigned*)((char*)d_ws + xp_bytes);
        xp_kernel<<<dim3(1024), dim3(256), 0, stream>>>(
            x, Wih_f, bih_f, bhh_f, Wih_b, bih_b, bhh_b, xp_ws);
        rnn_serial2<<<dim3(2 * BB), dim3(128), 0, stream>>>(
            Whh_f, Whh_b, xp_ws, (unsigned short*)y_ws);
        out_kernel<<<dim3(2048), dim3(256), 0, stream>>>(y_ws, Wout, bout, out);
    } else {
        hipMemsetAsync(d_out, 0, (size_t)out_size * sizeof(float), stream);
        birnn_fused<<<dim3(2 * BB), dim3(256), 0, stream>>>(
            x, Wih_f, Whh_f, bih_f, bhh_f,
            Wih_b, Whh_b, bih_b, bhh_b, Wout, bout, out);
    }
}

// Round 6
// 1262.373 us; speedup vs baseline: 2.2560x; 1.0584x over previous
//
#include <hip/hip_runtime.h>
#include <hip/hip_bf16.h>

typedef float f2 __attribute__((ext_vector_type(2)));
typedef float f4 __attribute__((ext_vector_type(4)));
typedef _Float16 h2 __attribute__((ext_vector_type(2)));
typedef _Float16 h8 __attribute__((ext_vector_type(8)));

#define BB 64
#define TT 2048
#define II 64
#define HH 128
#define OO 64

// ---------- f16 pair helpers ----------
__device__ __forceinline__ unsigned pack_h16(float a, float b) {
    h2 p; p.x = (_Float16)a; p.y = (_Float16)b;   // v_cvt_f16_f32 is RNE
    return __builtin_bit_cast(unsigned, p);
}
__device__ __forceinline__ float h16_lo(unsigned u) {
    h2 p = __builtin_bit_cast(h2, u); return (float)p.x;
}
__device__ __forceinline__ float h16_hi(unsigned u) {
    h2 p = __builtin_bit_cast(h2, u); return (float)p.y;
}
__device__ __forceinline__ float fdot2w(h2 a, h2 b, float c) {
#if __has_builtin(__builtin_amdgcn_fdot2)
    return __builtin_amdgcn_fdot2(a, b, c, false);   // v_dot2_f32_f16, f32 acc
#else
    return c + (float)a.x * (float)b.x + (float)a.y * (float)b.y;
#endif
}

// =====================================================================
// Kernel 1: xp[d][b][t][pair] (f16 pairs) = x[b,t,:]·Wih_d[h,:] + bih + bhh
// f32 math, f16 output pack. (Known-good structure from rounds 4/5.)
// =====================================================================
__global__ __launch_bounds__(256, 1)
void xp_kernel(const float* __restrict__ x,
               const float* __restrict__ Wih_f, const float* __restrict__ bih_f,
               const float* __restrict__ bhh_f,
               const float* __restrict__ Wih_b, const float* __restrict__ bih_b,
               const float* __restrict__ bhh_b,
               unsigned* __restrict__ xp)
{
    const int blk = blockIdx.x;
    const int tt = blk & 7;
    const int b  = (blk >> 3) & 63;
    const int d  = blk >> 9;
    const float* __restrict__ Wih = d ? Wih_b : Wih_f;
    const float* __restrict__ bih = d ? bih_b : bih_f;
    const float* __restrict__ bhh = d ? bhh_b : bhh_f;

    const int tid = threadIdx.x;
    const int w   = tid >> 6;
    const int l   = tid & 63;

    __shared__ float xs[256 * II];   // 64 KiB

    const float* xsrc = x + ((size_t)b * TT + (size_t)tt * 256) * II;
    for (int i = tid; i < 256 * II / 4; i += 256)
        ((f4*)xs)[i] = ((const f4*)xsrc)[i];

    f2 w0[32], w1[32];
    {
        const f4* s0 = (const f4*)(Wih + (size_t)(2 * l) * II);
        const f4* s1 = (const f4*)(Wih + (size_t)(2 * l + 1) * II);
        #pragma unroll
        for (int m = 0; m < 16; ++m) {
            f4 v0 = s0[m], v1 = s1[m];
            w0[2 * m] = (f2){v0.x, v0.y}; w0[2 * m + 1] = (f2){v0.z, v0.w};
            w1[2 * m] = (f2){v1.x, v1.y}; w1[2 * m + 1] = (f2){v1.z, v1.w};
        }
    }
    const float bias0 = bih[2 * l]     + bhh[2 * l];
    const float bias1 = bih[2 * l + 1] + bhh[2 * l + 1];
    __syncthreads();

    unsigned* xpd = xp + ((size_t)(d * BB + b) * TT + (size_t)tt * 256) * (HH / 2);
    for (int ti = 0; ti < 64; ++ti) {
        const int t_loc = w * 64 + ti;
        const f4* xr = (const f4*)(xs + t_loc * II);
        f2 a0 = (f2){0, 0}, a0b = (f2){0, 0}, a1 = (f2){0, 0}, a1b = (f2){0, 0};
        #pragma unroll
        for (int m = 0; m < 16; ++m) {
            f4 v = xr[m];
            f2 lo = (f2){v.x, v.y}, hi = (f2){v.z, v.w};
            a0  += w0[2 * m] * lo;  a0b += w0[2 * m + 1] * hi;
            a1  += w1[2 * m] * lo;  a1b += w1[2 * m + 1] * hi;
        }
        float z0 = a0.x + a0.y + a0b.x + a0b.y + bias0;
        float z1 = a1.x + a1.y + a1b.x + a1b.y + bias1;
        xpd[(size_t)t_loc * (HH / 2) + l] = pack_h16(z0, z1);
    }
}

// =====================================================================
// Kernel 2: serial recurrence v3 — ONE WAVE per (b,d).
//   * No barriers at all (single-wave DS ops are in-order).
//   * W_hh as f16 pairs in registers: 2 rows/lane = 128 VGPRs (the
//     footprint that provably stays resident — round-5 evidence).
//   * h as f16 pairs in LDS: full h = 256 B -> 16 uniform ds_read_b128
//     per step (halves round-5's LDS pipe; no second wave re-reading).
//   * v_dot2_f32_f16 (f32 accumulate) for the matvec; 8 acc chains.
//   * xp prefetched 2 steps ahead; y stored as f16 pairs; neither is
//     ever waited on the critical path.
// =====================================================================
__global__
__attribute__((amdgpu_flat_work_group_size(64, 64), amdgpu_waves_per_eu(1, 1)))
void rnn_serial3(const float* __restrict__ Whh_f, const float* __restrict__ Whh_b,
                 const unsigned* __restrict__ xp, unsigned* __restrict__ y)
{
    const int l = threadIdx.x;          // lane: owns rows 2l, 2l+1
    const int b = blockIdx.x & 63;
    const int d = blockIdx.x >> 6;
    const float* __restrict__ Whh = d ? Whh_b : Whh_f;

    __shared__ unsigned hb[2][HH / 2];  // f16 pairs, 256 B per buffer

    // rows 2l, 2l+1 of Whh -> f16 pairs in registers (64 + 64 VGPRs)
    h2 w0[64], w1[64];
    {
        const f4* s0 = (const f4*)(Whh + (size_t)(2 * l) * HH);
        const f4* s1 = (const f4*)(Whh + (size_t)(2 * l + 1) * HH);
        #pragma unroll
        for (int m = 0; m < 32; ++m) {
            f4 v0 = s0[m], v1 = s1[m];
            w0[2 * m]     = (h2){(_Float16)v0.x, (_Float16)v0.y};
            w0[2 * m + 1] = (h2){(_Float16)v0.z, (_Float16)v0.w};
            w1[2 * m]     = (h2){(_Float16)v1.x, (_Float16)v1.y};
            w1[2 * m + 1] = (h2){(_Float16)v1.z, (_Float16)v1.w};
        }
    }

    hb[0][l] = 0u;   // h0 = 0 (f16 pair)

    const size_t base_pair = (size_t)(d * BB + b) * TT * (HH / 2);
    const unsigned* xpl = xp + base_pair + l;
    unsigned*       yl  = y  + base_pair + l;

    const int t0 = d ? (TT - 1) : 0;
    const int dt = d ? -1 : 1;

    unsigned xc = xpl[(size_t)t0 * (HH / 2)];
    unsigned xn = xpl[(size_t)(t0 + dt) * (HH / 2)];

    #pragma unroll 2
    for (int s = 0; s < TT; ++s) {
        const int cur = s & 1, nxt = cur ^ 1;

        // prefetch xp for s+2 — never waited this iteration
        unsigned xf = 0;
        if (s + 2 < TT) xf = xpl[(size_t)(t0 + dt * (s + 2)) * (HH / 2)];

        // z = Whh·h : 16 uniform b128 reads, 128 dot2, 8 acc chains
        const h8* hr = (const h8*)hb[cur];
        float a00 = 0, a01 = 0, a02 = 0, a03 = 0;
        float a10 = 0, a11 = 0, a12 = 0, a13 = 0;
        #pragma unroll
        for (int m = 0; m < 16; ++m) {
            h8 v = hr[m];
            h2 p0 = __builtin_shufflevector(v, v, 0, 1);
            h2 p1 = __builtin_shufflevector(v, v, 2, 3);
            h2 p2 = __builtin_shufflevector(v, v, 4, 5);
            h2 p3 = __builtin_shufflevector(v, v, 6, 7);
            a00 = fdot2w(w0[4 * m],     p0, a00);
            a01 = fdot2w(w0[4 * m + 1], p1, a01);
            a02 = fdot2w(w0[4 * m + 2], p2, a02);
            a03 = fdot2w(w0[4 * m + 3], p3, a03);
            a10 = fdot2w(w1[4 * m],     p0, a10);
            a11 = fdot2w(w1[4 * m + 1], p1, a11);
            a12 = fdot2w(w1[4 * m + 2], p2, a12);
            a13 = fdot2w(w1[4 * m + 3], p3, a13);
        }
        float z0 = (a00 + a01) + (a02 + a03) + h16_lo(xc);
        float z1 = (a10 + a11) + (a12 + a13) + h16_hi(xc);

        // tanh(z) = 1 - 2/(e^{2z}+1), inf-safe
        float e0 = __expf(2.f * z0);
        float e1 = __expf(2.f * z1);
        float h0 = 1.f - __fdividef(2.f, e0 + 1.f);
        float h1 = 1.f - __fdividef(2.f, e1 + 1.f);

        const unsigned hp = pack_h16(h0, h1);
        hb[nxt][l] = hp;                              // DS in-order: no wait needed
        yl[(size_t)(t0 + dt * s) * (HH / 2)] = hp;    // streamed, never waited

        xc = xn; xn = xf;
    }
}

// =====================================================================
// Kernel 3: out[b][t][o] = Wout·[y_f;y_b] + bout  (f16 y, f32 math)
// =====================================================================
__global__ __launch_bounds__(256, 1)
void out_kernel(const unsigned* __restrict__ y, const float* __restrict__ Wout,
                const float* __restrict__ bout, float* __restrict__ out)
{
    const int blk = blockIdx.x;
    const int tt = blk & 31;
    const int b  = blk >> 5;
    const int tid = threadIdx.x;
    const int w = tid >> 6, l = tid & 63;

    __shared__ float ys[64][2 * HH];   // 64 KiB

    const unsigned* yf = y + ((size_t)(0 * BB + b) * TT + (size_t)tt * 64) * (HH / 2);
    const unsigned* yb = y + ((size_t)(1 * BB + b) * TT + (size_t)tt * 64) * (HH / 2);
    for (int i = tid; i < 64 * (HH / 2); i += 256) {
        const int t_loc = i >> 6, hp = i & 63;
        unsigned vf = yf[i], vb = yb[i];
        ys[t_loc][2 * hp]          = h16_lo(vf);
        ys[t_loc][2 * hp + 1]      = h16_hi(vf);
        ys[t_loc][HH + 2 * hp]     = h16_lo(vb);
        ys[t_loc][HH + 2 * hp + 1] = h16_hi(vb);
    }

    const int o  = 32 * (w & 1) + (l >> 1);
    const int ks = l & 1;
    f2 wv[64];
    {
        const f4* s = (const f4*)(Wout + (size_t)o * (2 * HH) + (size_t)ks * HH);
        #pragma unroll
        for (int m = 0; m < 32; ++m) {
            f4 v = s[m];
            wv[2 * m] = (f2){v.x, v.y}; wv[2 * m + 1] = (f2){v.z, v.w};
        }
    }
    const float bo = bout[o];
    __syncthreads();

    for (int i = 0; i < 32; ++i) {
        const int t_loc = 2 * i + (w >> 1);
        const f4* yr = (const f4*)(&ys[t_loc][ks * HH]);
        f2 acc = (f2){0, 0}, accb = (f2){0, 0};
        #pragma unroll
        for (int m = 0; m < 32; ++m) {
            f4 v = yr[m];
            acc  += wv[2 * m]     * (f2){v.x, v.y};
            accb += wv[2 * m + 1] * (f2){v.z, v.w};
        }
        float r = acc.x + acc.y + accb.x + accb.y;
        r += __shfl_xor(r, 1);
        if (ks == 0)
            out[((size_t)b * TT + (size_t)tt * 64 + t_loc) * OO + o] = r + bo;
    }
}

// =====================================================================
// Fallback (ws too small): known-good fused kernel from round 3 (1689 us).
// =====================================================================
__global__ __launch_bounds__(256, 1)
void birnn_fused(const float* __restrict__ x,
                 const float* __restrict__ Wih_f, const float* __restrict__ Whh_f,
                 const float* __restrict__ bih_f, const float* __restrict__ bhh_f,
                 const float* __restrict__ Wih_b, const float* __restrict__ Whh_b,
                 const float* __restrict__ bih_b, const float* __restrict__ bhh_b,
                 const float* __restrict__ Wout, const float* __restrict__ bout,
                 float* __restrict__ out)
{
    const int tid = threadIdx.x;
    const int b   = blockIdx.x & (BB - 1);
    const int d   = blockIdx.x >> 6;
    const float* __restrict__ Wih = d ? Wih_b : Wih_f;
    const float* __restrict__ Whh = d ? Whh_b : Whh_f;
    const float* __restrict__ bih = d ? bih_b : bih_f;
    const float* __restrict__ bhh = d ? bhh_b : bhh_f;
    const int j = tid >> 1, p = tid & 1, o = tid >> 2, os = tid & 3;
    __shared__ float hbuf[2][HH];
    __shared__ float xbuf[2][II];
    f2 whh[32], wih[16], wo[16];
    {
        const f4* s4 = (const f4*)(Whh + (size_t)j * HH + p * 64);
        #pragma unroll
        for (int m = 0; m < 16; ++m) { f4 v = s4[m]; whh[2*m]=(f2){v.x,v.y}; whh[2*m+1]=(f2){v.z,v.w}; }
    }
    {
        const f4* s4 = (const f4*)(Wih + (size_t)j * II + p * 32);
        #pragma unroll
        for (int m = 0; m < 8; ++m) { f4 v = s4[m]; wih[2*m]=(f2){v.x,v.y}; wih[2*m+1]=(f2){v.z,v.w}; }
    }
    {
        const f4* s4 = (const f4*)(Wout + (size_t)o * (2*HH) + d*HH + os*32);
        #pragma unroll
        for (int m = 0; m < 8; ++m) { f4 v = s4[m]; wo[2*m]=(f2){v.x,v.y}; wo[2*m+1]=(f2){v.z,v.w}; }
    }
    const float bj = bih[j] + bhh[j];
    const float bo = d ? 0.f : bout[o];
    const float* __restrict__ xb   = x   + (size_t)b * TT * II;
    float*       __restrict__ outb = out + (size_t)b * TT * OO;
    const int t0 = d ? (TT - 1) : 0;
    const int dt = d ? -1 : 1;
    float xpre = 0.f;
    if (tid < II) {
        xbuf[0][tid] = xb[(size_t)t0 * II + tid];
        xpre = xb[(size_t)(t0 + dt) * II + tid];
    }
    if (tid < HH) hbuf[0][tid] = 0.f;
    __syncthreads();
    #pragma unroll 2
    for (int s = 0; s < TT; ++s) {
        const int cur = s & 1, nxt = cur ^ 1;
        if (s > 0) {
            const f4* hv4 = (const f4*)(&hbuf[cur][os * 32]);
            f2 acc = (f2){0.f, 0.f};
            #pragma unroll
            for (int m = 0; m < 8; ++m) { f4 h4 = hv4[m]; acc += wo[2*m]*(f2){h4.x,h4.y}; acc += wo[2*m+1]*(f2){h4.z,h4.w}; }
            float v = acc.x + acc.y;
            v += __shfl_xor(v, 1); v += __shfl_xor(v, 2);
            if (os == 0) atomicAdd(&outb[(size_t)(t0 + dt*(s-1)) * OO + o], v + bo);
        }
        {
            const f4* hv4 = (const f4*)(&hbuf[cur][p * 64]);
            const f4* xv4 = (const f4*)(&xbuf[cur][p * 32]);
            f2 acc = (f2){0.f, 0.f};
            #pragma unroll
            for (int m = 0; m < 16; ++m) { f4 h4 = hv4[m]; acc += whh[2*m]*(f2){h4.x,h4.y}; acc += whh[2*m+1]*(f2){h4.z,h4.w}; }
            #pragma unroll
            for (int m = 0; m < 8; ++m) { f4 x4 = xv4[m]; acc += wih[2*m]*(f2){x4.x,x4.y}; acc += wih[2*m+1]*(f2){x4.z,x4.w}; }
            float z = acc.x + acc.y;
            z += __shfl_xor(z, 1);
            z += bj;
            float e = __expf(2.f * z);
            float h = 1.f - __fdividef(2.f, e + 1.f);
            if (p == 0) hbuf[nxt][j] = h;
        }
        if (tid < II) {
            xbuf[nxt][tid] = xpre;
            if (s + 2 < TT) xpre = xb[(size_t)(t0 + dt*(s+2)) * II + tid];
        }
        __syncthreads();
    }
    {
        const f4* hv4 = (const f4*)(&hbuf[TT & 1][os * 32]);
        f2 acc = (f2){0.f, 0.f};
        #pragma unroll
        for (int m = 0; m < 8; ++m) { f4 h4 = hv4[m]; acc += wo[2*m]*(f2){h4.x,h4.y}; acc += wo[2*m+1]*(f2){h4.z,h4.w}; }
        float v = acc.x + acc.y;
        v += __shfl_xor(v, 1); v += __shfl_xor(v, 2);
        if (os == 0) atomicAdd(&outb[(size_t)(t0 + dt*(TT-1)) * OO + o], v + bo);
    }
}

extern "C" void kernel_launch(void* const* d_in, const int* in_sizes, int n_in,
                              void* d_out, int out_size, void* d_ws, size_t ws_size,
                              hipStream_t stream) {
    const float* x     = (const float*)d_in[0];
    const float* Wih_f = (const float*)d_in[1];
    const float* Whh_f = (const float*)d_in[2];
    const float* bih_f = (const float*)d_in[3];
    const float* bhh_f = (const float*)d_in[4];
    const float* Wih_b = (const float*)d_in[5];
    const float* Whh_b = (const float*)d_in[6];
    const float* bih_b = (const float*)d_in[7];
    const float* bhh_b = (const float*)d_in[8];
    const float* Wout  = (const float*)d_in[9];
    const float* bout  = (const float*)d_in[10];
    float* out = (float*)d_out;

    const size_t xp_bytes = (size_t)2 * BB * TT * (HH / 2) * 4;  // 64 MiB (f16 pairs)
    const size_t y_bytes  = xp_bytes;                             // 64 MiB
    if (ws_size >= xp_bytes + y_bytes) {
        unsigned* xp_ws = (unsigned*)d_ws;
        unsigned* y_ws  = (unsigned*)((char*)d_ws + xp_bytes);
        xp_kernel<<<dim3(1024), dim3(256), 0, stream>>>(
            x, Wih_f, bih_f, bhh_f, Wih_b, bih_b, bhh_b, xp_ws);
        rnn_serial3<<<dim3(2 * BB), dim3(64), 0, stream>>>(
            Whh_f, Whh_b, xp_ws, y_ws);
        out_kernel<<<dim3(2048), dim3(256), 0, stream>>>(y_ws, Wout, bout, out);
    } else {
        hipMemsetAsync(d_out, 0, (size_t)out_size * sizeof(float), stream);
        birnn_fused<<<dim3(2 * BB), dim3(256), 0, stream>>>(
            x, Wih_f, Whh_f, bih_f, bhh_f,
            Wih_b, Whh_b, bih_b, bhh_b, Wout, bout, out);
    }
}